// Round 1
// baseline (223.053 us; speedup 1.0000x reference)
//
#include <hip/hip_runtime.h>

// GlobalShift2dV2Portion: x (16, 512, 64, 64) f32.
// ch < 256  : identity copy.
// ch >= 256 : 64x64 image = 4x4 grid of 16x16 blocks; block t_out=(h/16)*4+(w/16)
//             reads from block t_in = (s + t_out) % 16, s = (ch-256)/16.
// Pure permutation at >=16B granularity -> float4 per thread, output-coalesced.

#define B 16
#define C 512
#define H 64
#define W 64
#define W4 (W / 4)   // 16 float4 per row

__global__ __launch_bounds__(256) void GlobalShift2dV2Portion_kernel(
    const float4* __restrict__ in, float4* __restrict__ out) {
    int i = blockIdx.x * 256 + threadIdx.x;   // float4 index, < B*C*H*W4 = 8388608
    int w4 = i & 15;          // w/4 within row; w = w4*4
    int t  = i >> 4;
    int h  = t & 63;
    int bc = t >> 6;          // b*C + ch
    int ch = bc & 511;
    if (ch < 256) {
        out[i] = in[i];
    } else {
        int s     = (ch - 256) >> 4;                          // [0,16)
        int t_in  = (s + ((h >> 4) << 2) + (w4 >> 2)) & 15;   // (s + a0*4 + b0) % 16
        int h_in  = ((t_in >> 2) << 4) | (h & 15);
        int w4_in = ((t_in & 3) << 2) | (w4 & 3);
        int j     = ((bc << 6) + h_in) * W4 + w4_in;
        out[i] = in[j];
    }
}

extern "C" void kernel_launch(void* const* d_in, const int* in_sizes, int n_in,
                              void* d_out, int out_size, void* d_ws, size_t ws_size,
                              hipStream_t stream) {
    const float4* in = (const float4*)d_in[0];
    float4* out = (float4*)d_out;
    int total4 = in_sizes[0] / 4;             // 8,388,608
    int blocks = total4 / 256;                // 32,768
    GlobalShift2dV2Portion_kernel<<<blocks, 256, 0, stream>>>(in, out);
}